// Round 16
// baseline (207.632 us; speedup 1.0000x reference)
//
#include <hip/hip_runtime.h>

#define NB 32768
#define NCH 8
#define ROWS 32  // rows per block -> 1024 blocks, 256 thr; LDS 40KB -> 4 blocks/CU

#define WAITL0 asm volatile("s_waitcnt lgkmcnt(0)" ::: "memory")

typedef __bf16 bf16x8 __attribute__((ext_vector_type(8)));
typedef float f32x4 __attribute__((ext_vector_type(4)));
typedef unsigned int u32;
typedef unsigned short u16;
typedef u32 u32x4v __attribute__((ext_vector_type(4)));
typedef u32 u32x2v __attribute__((ext_vector_type(2)));

// bf16 weights, transposed to [n][k]. Order: 0=Wi 1=Wf 2=Wo 3=Wu 4=Ui 5=Uf 6=Uo 7=Uu
__device__ __align__(16) u16 g_wt[8 * 128 * 128];

__device__ __forceinline__ u16 f2bf(float f) {
  u32 u = __builtin_bit_cast(u32, f);
  u32 r = u + 0x7FFFu + ((u >> 16) & 1u);  // RNE
  return (u16)(r >> 16);
}
__device__ __forceinline__ float bf2f(u16 b) {
  u32 u = (u32)b << 16;
  return __builtin_bit_cast(float, u);
}
__device__ __forceinline__ float sigm(float s) {
  return __builtin_amdgcn_rcpf(1.0f + __expf(-s));
}
__device__ __forceinline__ float tanh_f(float v) {
  float e = __expf(2.0f * v);
  return 1.0f - 2.0f * __builtin_amdgcn_rcpf(e + 1.0f);
}

__global__ void prep_weights(const float* __restrict__ Wi, const float* __restrict__ Wf,
                             const float* __restrict__ Wo, const float* __restrict__ Wu,
                             const float* __restrict__ Ui, const float* __restrict__ Uf,
                             const float* __restrict__ Uo, const float* __restrict__ Uu) {
  __shared__ float t[128][129];
  const float* srcs[8] = {Wi, Wf, Wo, Wu, Ui, Uf, Uo, Uu};
  const float* s = srcs[blockIdx.x];
  for (int i = threadIdx.x; i < 16384; i += 256) t[i >> 7][i & 127] = s[i];
  __syncthreads();
  u16* dst = g_wt + blockIdx.x * 16384;
  for (int i = threadIdx.x; i < 16384; i += 256) {
    int n = i >> 7, k = i & 127;
    dst[i] = f2bf(t[k][n]);
  }
}

// ---------- bf16 swizzled tile (x, h, h_tilde) ----------
__device__ __forceinline__ bf16x8 ldA(const u32x4v* buf, int row, int ks, int g) {
  u32x4v v = buf[row * 16 + ((ks * 4 + g) ^ (row & 7))];
  return __builtin_bit_cast(bf16x8, v);
}
__device__ __forceinline__ bf16x8 ldB(const u16* wt, int col, int ks, int g) {
  return __builtin_bit_cast(bf16x8, *(const u32x4v*)(wt + col * 128 + ks * 32 + g * 8));
}

// staging layout: thread owns rows (tid>>5)+i*8, dwords (tid&31)*4..+3
__device__ __forceinline__ void stage_load(const float* __restrict__ src, int tid, f32x4 v[4]) {
#pragma unroll
  for (int i = 0; i < 4; ++i) {
    int q = tid + (i << 8);
    v[i] = *(const f32x4*)(src + (q >> 5) * 128 + (q & 31) * 4);
  }
}
__device__ __forceinline__ u32x2v pack2(f32x4 v) {
  u32x2v p;
  p[0] = (u32)f2bf(v[0]) | ((u32)f2bf(v[1]) << 16);
  p[1] = (u32)f2bf(v[2]) | ((u32)f2bf(v[3]) << 16);
  return p;
}
__device__ __forceinline__ void stage_write(u32x4v* buf, int tid, const f32x4 v[4]) {
  u32x2v* b2 = (u32x2v*)buf;
#pragma unroll
  for (int i = 0; i < 4; ++i) {
    int q = tid + (i << 8);
    int r = q >> 5, c4 = q & 31;
    b2[r * 32 + (c4 ^ ((r & 7) << 1))] = pack2(v[i]);
  }
}

// commit reg-staged child to LDS (both bf16):
// h -> xs-format swizzle; C -> element (row,col) at row*128 + (col ^ (k<<4)), k=(row>>2)&3.
// Write: 4 bf16 group -> u32x2v index r*32 + (c4 ^ (k<<2)).  (max 1023, in-bounds)
// h_tilde accumulated in f32 BEFORE conversion (exact).
__device__ __forceinline__ void commit_tiles(u32x4v* hdst, u16* cdst, int tid,
                                             const f32x4 hv[4], const f32x4 cv[4],
                                             f32x4 htacc[4]) {
  u32x2v* hb2 = (u32x2v*)hdst;
  u32x2v* cb2 = (u32x2v*)cdst;
#pragma unroll
  for (int i = 0; i < 4; ++i) {
    int q = tid + (i << 8);
    int r = q >> 5, c4 = q & 31;
    htacc[i] += hv[i];
    hb2[r * 32 + (c4 ^ ((r & 7) << 1))] = pack2(hv[i]);
    cb2[r * 32 + (c4 ^ (((r >> 2) & 3) << 2))] = pack2(cv[i]);
  }
}

// acc[2][2] += A(32x128 bf16 LDS) @ B(128 x 32 cols of Wt)
__device__ __forceinline__ void gemm_g(const u32x4v* a, const u16* wt, int cl, int g,
                                       int cb, f32x4 acc[2][2]) {
#pragma unroll
  for (int ks = 0; ks < 4; ++ks) {
    bf16x8 b0 = ldB(wt, cb + cl, ks, g);
    bf16x8 b1 = ldB(wt, cb + 16 + cl, ks, g);
    bf16x8 a0 = ldA(a, cl, ks, g);
    bf16x8 a1 = ldA(a, 16 + cl, ks, g);
    acc[0][0] = __builtin_amdgcn_mfma_f32_16x16x32_bf16(a0, b0, acc[0][0], 0, 0, 0);
    acc[0][1] = __builtin_amdgcn_mfma_f32_16x16x32_bf16(a0, b1, acc[0][1], 0, 0, 0);
    acc[1][0] = __builtin_amdgcn_mfma_f32_16x16x32_bf16(a1, b0, acc[1][0], 0, 0, 0);
    acc[1][1] = __builtin_amdgcn_mfma_f32_16x16x32_bf16(a1, b1, acc[1][1], 0, 0, 0);
  }
}

// fex exchange (epilogue only; ex = 32x128 f32 scratch)
__device__ __forceinline__ int fxsw(int row, int dw) {
  int k = (row >> 2) & 3;
  return row * 128 + (dw ^ (((k & 1) << 4) | ((k >> 1) << 2)));
}
__device__ __forceinline__ void exch(float* ex, const f32x4 fr[2][2], int g, int cl,
                                     int cb, int tid, f32x4 s4[4]) {
  __syncthreads();
#pragma unroll
  for (int m = 0; m < 2; ++m)
#pragma unroll
    for (int nf = 0; nf < 2; ++nf) {
      int col = cb + nf * 16 + cl;
#pragma unroll
      for (int r_ = 0; r_ < 4; ++r_)
        ex[fxsw(m * 16 + g * 4 + r_, col)] = fr[m][nf][r_];
    }
  __syncthreads();
  int sr = tid >> 5, sc = (tid & 31) * 4;
#pragma unroll
  for (int i = 0; i < 4; ++i)
    s4[i] = *(const f32x4*)(ex + fxsw(sr + i * 8, sc));
}

// compute one child: f-GEMM (bf16 LDS) + fused f-gate epilogue (bf16 C LDS)
__device__ __forceinline__ void child_compute(const u32x4v* hcur, const u16* ccur,
                                              const bf16x8 uf0[4], const bf16x8 uf1[4],
                                              const f32x4 afx[2][2], float bf0, float bf1,
                                              int cl, int g, int cb, f32x4 accc[2][2]) {
  f32x4 f[2][2];
#pragma unroll
  for (int m = 0; m < 2; ++m) { f[m][0] = afx[m][0]; f[m][1] = afx[m][1]; }
#pragma unroll
  for (int ks = 0; ks < 4; ++ks) {
    bf16x8 a0 = ldA(hcur, cl, ks, g);
    bf16x8 a1 = ldA(hcur, 16 + cl, ks, g);
    f[0][0] = __builtin_amdgcn_mfma_f32_16x16x32_bf16(a0, uf0[ks], f[0][0], 0, 0, 0);
    f[0][1] = __builtin_amdgcn_mfma_f32_16x16x32_bf16(a0, uf1[ks], f[0][1], 0, 0, 0);
    f[1][0] = __builtin_amdgcn_mfma_f32_16x16x32_bf16(a1, uf0[ks], f[1][0], 0, 0, 0);
    f[1][1] = __builtin_amdgcn_mfma_f32_16x16x32_bf16(a1, uf1[ks], f[1][1], 0, 0, 0);
  }
#pragma unroll
  for (int m = 0; m < 2; ++m)
#pragma unroll
    for (int nf = 0; nf < 2; ++nf) {
      float bfv = nf ? bf1 : bf0;
#pragma unroll
      for (int r = 0; r < 4; ++r) {
        int row = m * 16 + g * 4 + r;
        int lc = (cb + nf * 16 + cl) ^ (g << 4);
        float cval = bf2f(ccur[row * 128 + lc]);
        accc[m][nf][r] += sigm(f[m][nf][r] + bfv) * cval;
      }
    }
}

__global__ __launch_bounds__(256, 4) void tree_lstm(
    const float* __restrict__ x, const float* __restrict__ h, const float* __restrict__ C,
    const float* __restrict__ b_i, const float* __restrict__ b_f,
    const float* __restrict__ b_o, const float* __restrict__ b_u,
    float* __restrict__ out) {
  __shared__ u32x4v hbf[2][ROWS * 16];  // 16KB: bf16 h double buffer (xs-format)
  __shared__ u16 cbf[2][ROWS * 128];    // 16KB: bf16 C double buffer (col-swizzled)
  __shared__ u32x4v xs[ROWS * 16];      // 8KB: bf16 swizzled x tile

  const int tid = threadIdx.x;
  const int lane = tid & 63;
  const int wv = tid >> 6;
  const int cb = wv * 32;
  const int row0 = blockIdx.x * ROWS;
  const int g = lane >> 4;
  const int cl = lane & 15;
  const int sr = tid >> 5;
  const int sc = (tid & 31) * 4;
  const f32x4 fz = {0.f, 0.f, 0.f, 0.f};

  // ---- prologue ----
  f32x4 xv[4];
  stage_load(x + (size_t)row0 * 128, tid, xv);
  const float bf0 = b_f[cb + cl], bf1 = b_f[cb + 16 + cl];
  const float bi0 = b_i[cb + cl], bi1 = b_i[cb + 16 + cl];
  const float bo0 = b_o[cb + cl], bo1 = b_o[cb + 16 + cl];
  const float bu0 = b_u[cb + cl], bu1 = b_u[cb + 16 + cl];

  stage_write(xs, tid, xv);
  __syncthreads();  // xs visible

  // child 0 reg-loads in flight under Uf/afx compute
  f32x4 hv[4], cv[4];
  stage_load(h + (size_t)row0 * 128, tid, hv);
  stage_load(C + (size_t)row0 * 128, tid, cv);
  __builtin_amdgcn_sched_barrier(0);

  bf16x8 uf0[4], uf1[4];
#pragma unroll
  for (int ks = 0; ks < 4; ++ks) {
    uf0[ks] = ldB(g_wt + 5 * 16384, cb + cl, ks, g);
    uf1[ks] = ldB(g_wt + 5 * 16384, cb + 16 + cl, ks, g);
  }
  f32x4 afx[2][2];
#pragma unroll
  for (int m = 0; m < 2; ++m) { afx[m][0] = fz; afx[m][1] = fz; }
  gemm_g(xs, g_wt + 1 * 16384, cl, g, cb, afx);

  f32x4 accc[2][2];
#pragma unroll
  for (int m = 0; m < 2; ++m) { accc[m][0] = fz; accc[m][1] = fz; }
  f32x4 htacc[4] = {fz, fz, fz, fz};

  // commit child 0, issue child 1 (stays in flight across the barrier)
  commit_tiles(hbf[0], cbf[0], tid, hv, cv, htacc);
  stage_load(h + ((size_t)NB + row0) * 128, tid, hv);
  stage_load(C + ((size_t)NB + row0) * 128, tid, cv);
  __builtin_amdgcn_sched_barrier(0);
  WAITL0;
  __builtin_amdgcn_s_barrier();  // raw barrier: does NOT drain vmcnt

  // ---- child loop: compute n | commit n+1 | issue n+2 | barrier ----
#pragma unroll 1
  for (int n = 0; n < NCH - 1; ++n) {
    child_compute(hbf[n & 1], cbf[n & 1], uf0, uf1, afx, bf0, bf1, cl, g, cb, accc);

    commit_tiles(hbf[(n + 1) & 1], cbf[(n + 1) & 1], tid, hv, cv, htacc);
    if (n < NCH - 2) {  // issue child n+2, pinned here
      stage_load(h + ((size_t)(n + 2) * NB + row0) * 128, tid, hv);
      stage_load(C + ((size_t)(n + 2) * NB + row0) * 128, tid, cv);
      __builtin_amdgcn_sched_barrier(0);
    }
    WAITL0;                        // ds writes + reads retired
    __builtin_amdgcn_s_barrier();  // buffer n+1 visible; buffer n free next iter
  }

  // ---- peeled child 7 (buf 1) ----
  child_compute(hbf[1], cbf[1], uf0, uf1, afx, bf0, bf1, cl, g, cb, accc);
  __syncthreads();  // all reads done before h_tilde overwrite

  // ---- h_tilde (f32 regs) -> bf16 xs-format tile in hbf[0] ----
  stage_write(hbf[0], tid, htacc);
  __syncthreads();
  const u32x4v* ht = hbf[0];
  float* ex = (float*)cbf;  // 16KB f32 scratch (C data dead)

  f32x4 pre[2][2], s4[4];

  // u = tanh(x@Wu + ht@Uu + bu)
#pragma unroll
  for (int m = 0; m < 2; ++m) { pre[m][0] = fz; pre[m][1] = fz; }
  gemm_g(xs, g_wt + 3 * 16384, cl, g, cb, pre);
  gemm_g(ht, g_wt + 7 * 16384, cl, g, cb, pre);
  f32x4 uF[2][2];
#pragma unroll
  for (int m = 0; m < 2; ++m)
#pragma unroll
    for (int nf = 0; nf < 2; ++nf) {
      float bv = nf ? bu1 : bu0;
#pragma unroll
      for (int r = 0; r < 4; ++r) uF[m][nf][r] = tanh_f(pre[m][nf][r] + bv);
    }

  // i gate -> c = i*u + accc
#pragma unroll
  for (int m = 0; m < 2; ++m) { pre[m][0] = fz; pre[m][1] = fz; }
  gemm_g(xs, g_wt + 0 * 16384, cl, g, cb, pre);
  gemm_g(ht, g_wt + 4 * 16384, cl, g, cb, pre);
  f32x4 cF[2][2], tF[2][2];
#pragma unroll
  for (int m = 0; m < 2; ++m)
#pragma unroll
    for (int nf = 0; nf < 2; ++nf) {
      float bv = nf ? bi1 : bi0;
#pragma unroll
      for (int r = 0; r < 4; ++r) {
        float cv2 = sigm(pre[m][nf][r] + bv) * uF[m][nf][r] + accc[m][nf][r];
        cF[m][nf][r] = cv2;
        tF[m][nf][r] = tanh_f(cv2);
      }
    }
  exch(ex, cF, g, cl, cb, tid, s4);
  float* outc = out + (size_t)NB * 128;
#pragma unroll
  for (int i = 0; i < 4; ++i)
    *(f32x4*)(outc + (size_t)(row0 + sr + i * 8) * 128 + sc) = s4[i];

  // o gate -> h_j
#pragma unroll
  for (int m = 0; m < 2; ++m) { pre[m][0] = fz; pre[m][1] = fz; }
  gemm_g(xs, g_wt + 2 * 16384, cl, g, cb, pre);
  gemm_g(ht, g_wt + 6 * 16384, cl, g, cb, pre);
  f32x4 hF[2][2];
#pragma unroll
  for (int m = 0; m < 2; ++m)
#pragma unroll
    for (int nf = 0; nf < 2; ++nf) {
      float bv = nf ? bo1 : bo0;
#pragma unroll
      for (int r = 0; r < 4; ++r)
        hF[m][nf][r] = sigm(pre[m][nf][r] + bv) * tF[m][nf][r];
    }
  exch(ex, hF, g, cl, cb, tid, s4);
#pragma unroll
  for (int i = 0; i < 4; ++i)
    *(f32x4*)(out + (size_t)(row0 + sr + i * 8) * 128 + sc) = s4[i];
}

extern "C" void kernel_launch(void* const* d_in, const int* in_sizes, int n_in,
                              void* d_out, int out_size, void* d_ws, size_t ws_size,
                              hipStream_t stream) {
  (void)in_sizes; (void)n_in; (void)out_size; (void)d_ws; (void)ws_size;
  const float* x = (const float*)d_in[0];
  const float* h = (const float*)d_in[1];
  const float* C = (const float*)d_in[2];

  prep_weights<<<8, 256, 0, stream>>>(
      (const float*)d_in[3], (const float*)d_in[4], (const float*)d_in[5],
      (const float*)d_in[6], (const float*)d_in[7], (const float*)d_in[8],
      (const float*)d_in[9], (const float*)d_in[10]);

  tree_lstm<<<NB / ROWS, 256, 0, stream>>>(
      x, h, C,
      (const float*)d_in[11], (const float*)d_in[12],
      (const float*)d_in[13], (const float*)d_in[14],
      (float*)d_out);
}

// Round 17
// 108.283 us; speedup vs baseline: 1.9175x; 1.9175x over previous
//
#include <hip/hip_runtime.h>

#define NB 32768
#define NCH 8
#define ROWS 32  // rows per block -> 1024 blocks, 256 thr; LDS 40KB -> 4 blocks/CU

#define WAITL0 asm volatile("s_waitcnt lgkmcnt(0)" ::: "memory")

typedef __bf16 bf16x8 __attribute__((ext_vector_type(8)));
typedef float f32x4 __attribute__((ext_vector_type(4)));
typedef unsigned int u32;
typedef unsigned short u16;
typedef u32 u32x4v __attribute__((ext_vector_type(4)));
typedef u32 u32x2v __attribute__((ext_vector_type(2)));

// bf16 weights, transposed to [n][k]. Order: 0=Wi 1=Wf 2=Wo 3=Wu 4=Ui 5=Uf 6=Uo 7=Uu
__device__ __align__(16) u16 g_wt[8 * 128 * 128];

__device__ __forceinline__ u16 f2bf(float f) {
  u32 u = __builtin_bit_cast(u32, f);
  u32 r = u + 0x7FFFu + ((u >> 16) & 1u);  // RNE
  return (u16)(r >> 16);
}
__device__ __forceinline__ float bf2f(u16 b) {
  u32 u = (u32)b << 16;
  return __builtin_bit_cast(float, u);
}
__device__ __forceinline__ float sigm(float s) {
  return __builtin_amdgcn_rcpf(1.0f + __expf(-s));
}
__device__ __forceinline__ float tanh_f(float v) {
  float e = __expf(2.0f * v);
  return 1.0f - 2.0f * __builtin_amdgcn_rcpf(e + 1.0f);
}

__global__ void prep_weights(const float* __restrict__ Wi, const float* __restrict__ Wf,
                             const float* __restrict__ Wo, const float* __restrict__ Wu,
                             const float* __restrict__ Ui, const float* __restrict__ Uf,
                             const float* __restrict__ Uo, const float* __restrict__ Uu) {
  __shared__ float t[128][129];
  const float* srcs[8] = {Wi, Wf, Wo, Wu, Ui, Uf, Uo, Uu};
  const float* s = srcs[blockIdx.x];
  for (int i = threadIdx.x; i < 16384; i += 256) t[i >> 7][i & 127] = s[i];
  __syncthreads();
  u16* dst = g_wt + blockIdx.x * 16384;
  for (int i = threadIdx.x; i < 16384; i += 256) {
    int n = i >> 7, k = i & 127;
    dst[i] = f2bf(t[k][n]);
  }
}

// ---------- bf16 swizzled tile (x, h, h_tilde) ----------
__device__ __forceinline__ bf16x8 ldA(const u32x4v* buf, int row, int ks, int g) {
  u32x4v v = buf[row * 16 + ((ks * 4 + g) ^ (row & 7))];
  return __builtin_bit_cast(bf16x8, v);
}
__device__ __forceinline__ bf16x8 ldB(const u16* wt, int col, int ks, int g) {
  return __builtin_bit_cast(bf16x8, *(const u32x4v*)(wt + col * 128 + ks * 32 + g * 8));
}

// staging layout: thread owns rows (tid>>5)+i*8, dwords (tid&31)*4..+3
__device__ __forceinline__ void stage_load(const float* __restrict__ src, int tid, f32x4 v[4]) {
#pragma unroll
  for (int i = 0; i < 4; ++i) {
    int q = tid + (i << 8);
    v[i] = *(const f32x4*)(src + (q >> 5) * 128 + (q & 31) * 4);
  }
}
__device__ __forceinline__ u32x2v pack2(f32x4 v) {
  u32x2v p;
  p[0] = (u32)f2bf(v[0]) | ((u32)f2bf(v[1]) << 16);
  p[1] = (u32)f2bf(v[2]) | ((u32)f2bf(v[3]) << 16);
  return p;
}
__device__ __forceinline__ void stage_write(u32x4v* buf, int tid, const f32x4 v[4]) {
  u32x2v* b2 = (u32x2v*)buf;
#pragma unroll
  for (int i = 0; i < 4; ++i) {
    int q = tid + (i << 8);
    int r = q >> 5, c4 = q & 31;
    b2[r * 32 + (c4 ^ ((r & 7) << 1))] = pack2(v[i]);
  }
}

// commit reg-staged child to LDS (both bf16):
// h -> xs-format swizzle; C -> element (row,col) at row*128 + (col ^ (k<<4)), k=(row>>2)&3.
// Write: 4 bf16 group -> u32x2v index r*32 + (c4 ^ (k<<2)).  (max 1023, in-bounds)
// h_tilde accumulated in f32 BEFORE conversion (exact).
__device__ __forceinline__ void commit_tiles(u32x4v* hdst, u16* cdst, int tid,
                                             const f32x4 hv[4], const f32x4 cv[4],
                                             f32x4 htacc[4]) {
  u32x2v* hb2 = (u32x2v*)hdst;
  u32x2v* cb2 = (u32x2v*)cdst;
#pragma unroll
  for (int i = 0; i < 4; ++i) {
    int q = tid + (i << 8);
    int r = q >> 5, c4 = q & 31;
    htacc[i] += hv[i];
    hb2[r * 32 + (c4 ^ ((r & 7) << 1))] = pack2(hv[i]);
    cb2[r * 32 + (c4 ^ (((r >> 2) & 3) << 2))] = pack2(cv[i]);
  }
}

// acc[2][2] += A(32x128 bf16 LDS) @ B(128 x 32 cols of Wt)
__device__ __forceinline__ void gemm_g(const u32x4v* a, const u16* wt, int cl, int g,
                                       int cb, f32x4 acc[2][2]) {
#pragma unroll
  for (int ks = 0; ks < 4; ++ks) {
    bf16x8 b0 = ldB(wt, cb + cl, ks, g);
    bf16x8 b1 = ldB(wt, cb + 16 + cl, ks, g);
    bf16x8 a0 = ldA(a, cl, ks, g);
    bf16x8 a1 = ldA(a, 16 + cl, ks, g);
    acc[0][0] = __builtin_amdgcn_mfma_f32_16x16x32_bf16(a0, b0, acc[0][0], 0, 0, 0);
    acc[0][1] = __builtin_amdgcn_mfma_f32_16x16x32_bf16(a0, b1, acc[0][1], 0, 0, 0);
    acc[1][0] = __builtin_amdgcn_mfma_f32_16x16x32_bf16(a1, b0, acc[1][0], 0, 0, 0);
    acc[1][1] = __builtin_amdgcn_mfma_f32_16x16x32_bf16(a1, b1, acc[1][1], 0, 0, 0);
  }
}

// fex exchange (epilogue only; ex = 32x128 f32 scratch)
__device__ __forceinline__ int fxsw(int row, int dw) {
  int k = (row >> 2) & 3;
  return row * 128 + (dw ^ (((k & 1) << 4) | ((k >> 1) << 2)));
}
__device__ __forceinline__ void exch(float* ex, const f32x4 fr[2][2], int g, int cl,
                                     int cb, int tid, f32x4 s4[4]) {
  __syncthreads();
#pragma unroll
  for (int m = 0; m < 2; ++m)
#pragma unroll
    for (int nf = 0; nf < 2; ++nf) {
      int col = cb + nf * 16 + cl;
#pragma unroll
      for (int r_ = 0; r_ < 4; ++r_)
        ex[fxsw(m * 16 + g * 4 + r_, col)] = fr[m][nf][r_];
    }
  __syncthreads();
  int sr = tid >> 5, sc = (tid & 31) * 4;
#pragma unroll
  for (int i = 0; i < 4; ++i)
    s4[i] = *(const f32x4*)(ex + fxsw(sr + i * 8, sc));
}

// compute one child: f-GEMM (bf16 LDS) + fused f-gate epilogue (bf16 C LDS)
__device__ __forceinline__ void child_compute(const u32x4v* hcur, const u16* ccur,
                                              const bf16x8 uf0[4], const bf16x8 uf1[4],
                                              const f32x4 afx[2][2], float bf0, float bf1,
                                              int cl, int g, int cb, f32x4 accc[2][2]) {
  f32x4 f[2][2];
#pragma unroll
  for (int m = 0; m < 2; ++m) { f[m][0] = afx[m][0]; f[m][1] = afx[m][1]; }
#pragma unroll
  for (int ks = 0; ks < 4; ++ks) {
    bf16x8 a0 = ldA(hcur, cl, ks, g);
    bf16x8 a1 = ldA(hcur, 16 + cl, ks, g);
    f[0][0] = __builtin_amdgcn_mfma_f32_16x16x32_bf16(a0, uf0[ks], f[0][0], 0, 0, 0);
    f[0][1] = __builtin_amdgcn_mfma_f32_16x16x32_bf16(a0, uf1[ks], f[0][1], 0, 0, 0);
    f[1][0] = __builtin_amdgcn_mfma_f32_16x16x32_bf16(a1, uf0[ks], f[1][0], 0, 0, 0);
    f[1][1] = __builtin_amdgcn_mfma_f32_16x16x32_bf16(a1, uf1[ks], f[1][1], 0, 0, 0);
  }
#pragma unroll
  for (int m = 0; m < 2; ++m)
#pragma unroll
    for (int nf = 0; nf < 2; ++nf) {
      float bfv = nf ? bf1 : bf0;
#pragma unroll
      for (int r = 0; r < 4; ++r) {
        int row = m * 16 + g * 4 + r;
        int lc = (cb + nf * 16 + cl) ^ (g << 4);
        float cval = bf2f(ccur[row * 128 + lc]);
        accc[m][nf][r] += sigm(f[m][nf][r] + bfv) * cval;
      }
    }
}

__global__ __launch_bounds__(256) void tree_lstm(
    const float* __restrict__ x, const float* __restrict__ h, const float* __restrict__ C,
    const float* __restrict__ b_i, const float* __restrict__ b_f,
    const float* __restrict__ b_o, const float* __restrict__ b_u,
    float* __restrict__ out) {
  __shared__ u32x4v hbf[2][ROWS * 16];  // 16KB: bf16 h double buffer (xs-format)
  __shared__ u16 cbf[2][ROWS * 128];    // 16KB: bf16 C double buffer (col-swizzled)
  __shared__ u32x4v xs[ROWS * 16];      // 8KB: bf16 swizzled x tile

  const int tid = threadIdx.x;
  const int lane = tid & 63;
  const int wv = tid >> 6;
  const int cb = wv * 32;
  const int row0 = blockIdx.x * ROWS;
  const int g = lane >> 4;
  const int cl = lane & 15;
  const int sr = tid >> 5;
  const int sc = (tid & 31) * 4;
  const f32x4 fz = {0.f, 0.f, 0.f, 0.f};

  // ---- prologue ----
  f32x4 xv[4];
  stage_load(x + (size_t)row0 * 128, tid, xv);
  const float bf0 = b_f[cb + cl], bf1 = b_f[cb + 16 + cl];
  const float bi0 = b_i[cb + cl], bi1 = b_i[cb + 16 + cl];
  const float bo0 = b_o[cb + cl], bo1 = b_o[cb + 16 + cl];
  const float bu0 = b_u[cb + cl], bu1 = b_u[cb + 16 + cl];

  stage_write(xs, tid, xv);
  __syncthreads();  // xs visible

  // child 0 reg-loads in flight under Uf/afx compute
  f32x4 hv[4], cv[4];
  stage_load(h + (size_t)row0 * 128, tid, hv);
  stage_load(C + (size_t)row0 * 128, tid, cv);
  __builtin_amdgcn_sched_barrier(0);

  bf16x8 uf0[4], uf1[4];
#pragma unroll
  for (int ks = 0; ks < 4; ++ks) {
    uf0[ks] = ldB(g_wt + 5 * 16384, cb + cl, ks, g);
    uf1[ks] = ldB(g_wt + 5 * 16384, cb + 16 + cl, ks, g);
  }
  f32x4 afx[2][2];
#pragma unroll
  for (int m = 0; m < 2; ++m) { afx[m][0] = fz; afx[m][1] = fz; }
  gemm_g(xs, g_wt + 1 * 16384, cl, g, cb, afx);

  f32x4 accc[2][2];
#pragma unroll
  for (int m = 0; m < 2; ++m) { accc[m][0] = fz; accc[m][1] = fz; }
  f32x4 htacc[4] = {fz, fz, fz, fz};

  // commit child 0, issue child 1 (stays in flight across the barrier)
  commit_tiles(hbf[0], cbf[0], tid, hv, cv, htacc);
  stage_load(h + ((size_t)NB + row0) * 128, tid, hv);
  stage_load(C + ((size_t)NB + row0) * 128, tid, cv);
  __builtin_amdgcn_sched_barrier(0);
  WAITL0;
  __builtin_amdgcn_s_barrier();  // raw barrier: does NOT drain vmcnt

  // ---- child loop: compute n | commit n+1 | issue n+2 | barrier ----
#pragma unroll 1
  for (int n = 0; n < NCH - 1; ++n) {
    child_compute(hbf[n & 1], cbf[n & 1], uf0, uf1, afx, bf0, bf1, cl, g, cb, accc);

    commit_tiles(hbf[(n + 1) & 1], cbf[(n + 1) & 1], tid, hv, cv, htacc);
    if (n < NCH - 2) {  // issue child n+2, pinned here
      stage_load(h + ((size_t)(n + 2) * NB + row0) * 128, tid, hv);
      stage_load(C + ((size_t)(n + 2) * NB + row0) * 128, tid, cv);
      __builtin_amdgcn_sched_barrier(0);
    }
    WAITL0;                        // ds writes + reads retired
    __builtin_amdgcn_s_barrier();  // buffer n+1 visible; buffer n free next iter
  }

  // ---- peeled child 7 (buf 1) ----
  child_compute(hbf[1], cbf[1], uf0, uf1, afx, bf0, bf1, cl, g, cb, accc);
  __syncthreads();  // all reads done before h_tilde overwrite

  // ---- h_tilde (f32 regs) -> bf16 xs-format tile in hbf[0] ----
  stage_write(hbf[0], tid, htacc);
  __syncthreads();
  const u32x4v* ht = hbf[0];
  float* ex = (float*)cbf;  // 16KB f32 scratch (C data dead)

  f32x4 pre[2][2], s4[4];

  // u = tanh(x@Wu + ht@Uu + bu)
#pragma unroll
  for (int m = 0; m < 2; ++m) { pre[m][0] = fz; pre[m][1] = fz; }
  gemm_g(xs, g_wt + 3 * 16384, cl, g, cb, pre);
  gemm_g(ht, g_wt + 7 * 16384, cl, g, cb, pre);
  f32x4 uF[2][2];
#pragma unroll
  for (int m = 0; m < 2; ++m)
#pragma unroll
    for (int nf = 0; nf < 2; ++nf) {
      float bv = nf ? bu1 : bu0;
#pragma unroll
      for (int r = 0; r < 4; ++r) uF[m][nf][r] = tanh_f(pre[m][nf][r] + bv);
    }

  // i gate -> c = i*u + accc
#pragma unroll
  for (int m = 0; m < 2; ++m) { pre[m][0] = fz; pre[m][1] = fz; }
  gemm_g(xs, g_wt + 0 * 16384, cl, g, cb, pre);
  gemm_g(ht, g_wt + 4 * 16384, cl, g, cb, pre);
  f32x4 cF[2][2], tF[2][2];
#pragma unroll
  for (int m = 0; m < 2; ++m)
#pragma unroll
    for (int nf = 0; nf < 2; ++nf) {
      float bv = nf ? bi1 : bi0;
#pragma unroll
      for (int r = 0; r < 4; ++r) {
        float cv2 = sigm(pre[m][nf][r] + bv) * uF[m][nf][r] + accc[m][nf][r];
        cF[m][nf][r] = cv2;
        tF[m][nf][r] = tanh_f(cv2);
      }
    }
  exch(ex, cF, g, cl, cb, tid, s4);
  float* outc = out + (size_t)NB * 128;
#pragma unroll
  for (int i = 0; i < 4; ++i)
    *(f32x4*)(outc + (size_t)(row0 + sr + i * 8) * 128 + sc) = s4[i];

  // o gate -> h_j
#pragma unroll
  for (int m = 0; m < 2; ++m) { pre[m][0] = fz; pre[m][1] = fz; }
  gemm_g(xs, g_wt + 2 * 16384, cl, g, cb, pre);
  gemm_g(ht, g_wt + 6 * 16384, cl, g, cb, pre);
  f32x4 hF[2][2];
#pragma unroll
  for (int m = 0; m < 2; ++m)
#pragma unroll
    for (int nf = 0; nf < 2; ++nf) {
      float bv = nf ? bo1 : bo0;
#pragma unroll
      for (int r = 0; r < 4; ++r)
        hF[m][nf][r] = sigm(pre[m][nf][r] + bv) * tF[m][nf][r];
    }
  exch(ex, hF, g, cl, cb, tid, s4);
#pragma unroll
  for (int i = 0; i < 4; ++i)
    *(f32x4*)(out + (size_t)(row0 + sr + i * 8) * 128 + sc) = s4[i];
}

extern "C" void kernel_launch(void* const* d_in, const int* in_sizes, int n_in,
                              void* d_out, int out_size, void* d_ws, size_t ws_size,
                              hipStream_t stream) {
  (void)in_sizes; (void)n_in; (void)out_size; (void)d_ws; (void)ws_size;
  const float* x = (const float*)d_in[0];
  const float* h = (const float*)d_in[1];
  const float* C = (const float*)d_in[2];

  prep_weights<<<8, 256, 0, stream>>>(
      (const float*)d_in[3], (const float*)d_in[4], (const float*)d_in[5],
      (const float*)d_in[6], (const float*)d_in[7], (const float*)d_in[8],
      (const float*)d_in[9], (const float*)d_in[10]);

  tree_lstm<<<NB / ROWS, 256, 0, stream>>>(
      x, h, C,
      (const float*)d_in[11], (const float*)d_in[12],
      (const float*)d_in[13], (const float*)d_in[14],
      (float*)d_out);
}